// Round 7
// baseline (306.146 us; speedup 1.0000x reference)
//
#include <hip/hip_runtime.h>

#define NUM_EMB 2048
#define DIM     128
#define NVEC    65536            // 64*32*32
// MARGIN: needs >= 2*approx_err + fp32-bucket slop (~2.6e-4). 1e-3 = 4x
// headroom. Proven R7/R8: absmax 0.0. DO NOT ENLARGE (R6's 4e-3 -> 1.9 ms rerank).
// Capture in v-space (v = dot - enorm/2); threshold uses MARGIN/2 in v-units
// == MARGIN in distance units. Superset-capture argument: thr = vmax_sofar -
// MARGIN/2 <= vmax_final - MARGIN/2 at every test => every code within MARGIN
// of the final best is captured. Rerank is exact => absmax 0.
#define MARGIN  1.0e-3f
#define CAP     32               // candidates/row; overflow -> cooperative block scan
#define CHUNK   512              // codes per LDS chunk (R15: visits 9->4)
#define NCHUNK  (NUM_EMB / CHUNK)
#define ES      136              // ushort stride/code in LDS: 272 B -> b128 reads spread banks
#define ZS      132              // float stride/z-row in LDS
#define RROWS   32               // R17: rerank rows/block (was 64)
#define RTHR    512              // R17: rerank threads/block (was 256)

typedef float  f32x4 __attribute__((ext_vector_type(4)));
typedef short  s16x8 __attribute__((ext_vector_type(8)));

// RNE float -> bf16 (finite inputs)
__device__ __forceinline__ ushort f2bf(float f) {
    unsigned u = __float_as_uint(f);
    u = (u + 0x7fffu + ((u >> 16) & 1u)) >> 16;
    return (ushort)u;
}

// ---------------------------------------------------------------------------
// numpy pairwise_sum replica for n=128 fp32 applied to v*v (bit-exact vs np —
// verified R2-R8 absmax 0.0).  DO NOT REASSOCIATE.
// ---------------------------------------------------------------------------
__device__ __forceinline__ float np_pairwise_sumsq_128(const float* __restrict__ p)
{
    float r[8];
    #pragma unroll
    for (int j = 0; j < 8; ++j) { float v = p[j]; r[j] = __fmul_rn(v, v); }
    #pragma unroll
    for (int i = 8; i < 128; i += 8)
        #pragma unroll
        for (int j = 0; j < 8; ++j) { float v = p[i + j]; r[j] = __fadd_rn(r[j], __fmul_rn(v, v)); }
    float s01 = __fadd_rn(r[0], r[1]);
    float s23 = __fadd_rn(r[2], r[3]);
    float s45 = __fadd_rn(r[4], r[5]);
    float s67 = __fadd_rn(r[6], r[7]);
    return __fadd_rn(__fadd_rn(s01, s23), __fadd_rn(s45, s67));
}

// exact fp32-replica dot over one 32-k slab (ascending k, single accumulator)
__device__ __forceinline__ float dot_seg(const float4* __restrict__ zp,
                                         const float4* __restrict__ ep,
                                         int seg, float dot)
{
    float4 e[8], zz[8];
    #pragma unroll
    for (int i = 0; i < 8; ++i) { e[i] = ep[seg * 8 + i]; zz[i] = zp[seg * 8 + i]; }
    #pragma unroll
    for (int i = 0; i < 8; ++i) {
        dot = fmaf(zz[i].x, e[i].x, dot);
        dot = fmaf(zz[i].y, e[i].y, dot);
        dot = fmaf(zz[i].z, e[i].z, dot);
        dot = fmaf(zz[i].w, e[i].w, dot);
    }
    return dot;
}

// ---------------------------------------------------------------------------
// Kernel 1: enorm (np-exact) + emb->bf16 + zero accum  (FROZEN, R15)
// ---------------------------------------------------------------------------
__global__ __launch_bounds__(256)
void prep_kernel(const float* __restrict__ emb,
                 float* __restrict__ enorm,
                 float* __restrict__ accum,
                 ushort* __restrict__ emb_bf)
{
    int g = blockIdx.x * 256 + threadIdx.x;
    if (g == 0) *accum = 0.0f;

    float4 v = ((const float4*)emb)[g];          // 65536 float4 == full emb
    ushort4 b;
    b.x = f2bf(v.x); b.y = f2bf(v.y); b.z = f2bf(v.z); b.w = f2bf(v.w);
    ((ushort4*)emb_bf)[g] = b;

    if (g < NUM_EMB)
        enorm[g] = np_pairwise_sumsq_128(emb + (size_t)g * DIM);
}

// ---------------------------------------------------------------------------
// Kernel 2: bf16-MFMA approx filter.  (FROZEN — R16 verified: B-fragment
// reuse, 2 M-tiles/wave x half-codes; left top-5 => < 110us.)
// ---------------------------------------------------------------------------
__global__ __launch_bounds__(1024, 4)
void approx_kernel(const float* __restrict__ z,
                   const ushort* __restrict__ emb_bf,
                   const float* __restrict__ enorm,
                   unsigned* __restrict__ cand_cnt,
                   ushort* __restrict__ cand)
{
    __shared__ __align__(16) ushort eS[CHUNK * ES];   // 139,264 B
    __shared__ float cS[CHUNK];                       //   2,048 B (-0.5*enorm)
    __shared__ float vS[16][32];                      //   2,048 B (pair max exchange)
    __shared__ unsigned cntS[256];                    //   1,024 B

    const int tid  = threadIdx.x;         // 0..1023
    const int w    = tid >> 6;            // wave 0..15
    const int lane = tid & 63;
    const int col  = lane & 15;           // m (A frag) / n (B frag) / D col
    const int quad = lane >> 4;           // k-group / D row-group
    const int rg   = w >> 1;              // row-group 0..7 (32 rows each)
    const int ch   = w & 1;               // code-half 0..1 (256 codes each)
    const int rowbase = blockIdx.x * 256 + rg * 32;

    if (tid < 256) cntS[tid] = 0u;

    // A-fragments: 2 M-tiles x 4 k-tiles, loaded once, fp32->bf16
    s16x8 afrag[2][4];
    #pragma unroll
    for (int mt = 0; mt < 2; ++mt) {
        const float* zr = z + (size_t)(rowbase + mt * 16 + col) * DIM;
        #pragma unroll
        for (int kt = 0; kt < 4; ++kt) {
            const float4* p = (const float4*)(zr + kt * 32 + quad * 8);
            float4 f0 = p[0], f1 = p[1];
            s16x8 a;
            a[0] = (short)f2bf(f0.x); a[1] = (short)f2bf(f0.y);
            a[2] = (short)f2bf(f0.z); a[3] = (short)f2bf(f0.w);
            a[4] = (short)f2bf(f1.x); a[5] = (short)f2bf(f1.y);
            a[6] = (short)f2bf(f1.z); a[7] = (short)f2bf(f1.w);
            afrag[mt][kt] = a;
        }
    }

    const ushort* eH = eS + ch * 256 * ES;   // this wave's code-half in LDS
    const float*  cH = cS + ch * 256;

    // vmax[i], i = mt*4 + r -> local row = mt*16 + quad*4 + r
    float vmax[8], thr[8];
    #pragma unroll
    for (int i = 0; i < 8; ++i) { vmax[i] = -3.0e38f; thr[i] = 3.0e38f; }

    // 4 visits over 4 chunks of 512 codes; capture active from the start.
    for (int vis = 0; vis < NCHUNK; ++vis) {
        if (vis > 0) __syncthreads();        // prev readers done; partner vS visible

        // stage chunk vis: 128 KB, 8 x uint4 per thread, coalesced
        const uint4* src = (const uint4*)(emb_bf + (size_t)vis * CHUNK * DIM);
        #pragma unroll
        for (int i = 0; i < 8; ++i) {
            int li = i * 1024 + tid;         // 0..8191
            int code = li >> 4, fc = li & 15;
            *(uint4*)&eS[code * ES + fc * 8] = src[li];
        }
        if (tid < CHUNK) cS[tid] = -0.5f * enorm[vis * CHUNK + tid];

        // fold partner half's row maxima (through visit vis-1) -> tight thr
        if (vis > 0) {
            #pragma unroll
            for (int i = 0; i < 8; ++i) {
                float v = fmaxf(vmax[i], vS[w ^ 1][(i >> 2) * 16 + quad * 4 + (i & 3)]);
                vmax[i] = v;
                thr[i]  = v - 0.5f * MARGIN;
            }
        }
        __syncthreads();                     // LDS chunk ready

        #pragma unroll 4
        for (int t = 0; t < 16; ++t) {       // 16 x 16 = this wave's 256 codes
            s16x8 bfrag[4];
            #pragma unroll
            for (int kt = 0; kt < 4; ++kt)
                bfrag[kt] = *(const s16x8*)&eH[(t * 16 + col) * ES + kt * 32 + quad * 8];

            float h = cH[t * 16 + col];      // -0.5*enorm of this code
            f32x4 a0 = {h, h, h, h};
            f32x4 a1 = {h, h, h, h};
            #pragma unroll
            for (int kt = 0; kt < 4; ++kt) {
                a0 = __builtin_amdgcn_mfma_f32_16x16x32_bf16(afrag[0][kt], bfrag[kt], a0, 0, 0, 0);
                a1 = __builtin_amdgcn_mfma_f32_16x16x32_bf16(afrag[1][kt], bfrag[kt], a1, 0, 0, 0);
            }

            #pragma unroll
            for (int r = 0; r < 4; ++r) {
                vmax[r]     = fmaxf(vmax[r],     a0[r]);
                vmax[4 + r] = fmaxf(vmax[4 + r], a1[r]);
            }

            // visit 0: threshold still forming -> refresh per-t BEFORE the
            // capture test (superset capture; see MARGIN note).
            if (vis == 0) {
                #pragma unroll
                for (int i = 0; i < 8; ++i) {
                    float v = vmax[i];
                    v = fmaxf(v, __shfl_xor(v, 1, 64));
                    v = fmaxf(v, __shfl_xor(v, 2, 64));
                    v = fmaxf(v, __shfl_xor(v, 4, 64));
                    v = fmaxf(v, __shfl_xor(v, 8, 64));
                    vmax[i] = v;
                    thr[i]  = v - 0.5f * MARGIN;
                }
            }

            const int code_g = vis * CHUNK + ch * 256 + t * 16 + col;
            #pragma unroll
            for (int r = 0; r < 4; ++r) {
                if (a0[r] >= thr[r]) {
                    int row_l = rg * 32 + quad * 4 + r;
                    unsigned pos = atomicAdd(&cntS[row_l], 1u);   // LDS atomic
                    if (pos < CAP)                                 // plain store
                        cand[(size_t)(blockIdx.x * 256 + row_l) * CAP + pos] = (ushort)code_g;
                }
                if (a1[r] >= thr[4 + r]) {
                    int row_l = rg * 32 + 16 + quad * 4 + r;
                    unsigned pos = atomicAdd(&cntS[row_l], 1u);
                    if (pos < CAP)
                        cand[(size_t)(blockIdx.x * 256 + row_l) * CAP + pos] = (ushort)code_g;
                }
            }
        }

        // end-of-visit refresh (vis0 already row-wide from per-t refresh)
        if (vis > 0) {
            #pragma unroll
            for (int i = 0; i < 8; ++i) {
                float v = vmax[i];
                v = fmaxf(v, __shfl_xor(v, 1, 64));
                v = fmaxf(v, __shfl_xor(v, 2, 64));
                v = fmaxf(v, __shfl_xor(v, 4, 64));
                v = fmaxf(v, __shfl_xor(v, 8, 64));
                vmax[i] = v;
                thr[i]  = v - 0.5f * MARGIN;
            }
        }
        // publish this wave's 32-row maxima for the partner wave
        if (col == 0) {
            #pragma unroll
            for (int i = 0; i < 8; ++i)
                vS[w][(i >> 2) * 16 + quad * 4 + (i & 3)] = vmax[i];
        }
    }

    // flush counts (coalesced); payloads already in global
    __syncthreads();
    if (tid < 256) cand_cnt[blockIdx.x * 256 + tid] = cntS[tid];
}

// ---------------------------------------------------------------------------
// Kernel 3: exact fp32-replica re-rank (R17 restructure for TLP).
//
// R16 post-mortem (first rerank counters ever): 110us, VALUBusy 6.5%, HBM
// 6.6%, occupancy 13% (~4 waves/CU) => latency-bound. Faults: (1) candidate
// loop = per-lane serial 512-cy exact-dot chains (ceil(cnt/4) deep) over
// lane-divergent 512B emb gathers (up to 64 distinct lines per wave instr,
// L1/TA serialization); (2) 4 lanes/row starves TLP, per-block serial time
// ~27us x 4 batches = 110us.
// R17: 512 thr x 32 rows, grid 2048. Candidate phase = one (row,ci) slot per
// thread (1024 slots, 2/thread, ~1.6 ACTIVE dots/thread) -> chains run in
// parallel across threads, gathers overlap via TLP. Per-row select = lex-min
// (s asc, j asc) over LDS slot arrays — order-independent, bit-identical to
// the old (s,j) rule. Per-dot accumulation order UNCHANGED (dot_seg).
// Overflow path: verified block-cooperative scan, 512 thr x 4 ascending codes.
// ---------------------------------------------------------------------------
__global__ __launch_bounds__(RTHR, 4)
void rerank_kernel(const float* __restrict__ z,
                   const float* __restrict__ emb,
                   const float* __restrict__ enorm,
                   const unsigned* __restrict__ cand_cnt,
                   const ushort* __restrict__ cand,
                   float* __restrict__ out_q,
                   float* __restrict__ out_idx_f,
                   float* __restrict__ accum)
{
    __shared__ float zs[RROWS * ZS];     // 16,896 B
    __shared__ float sL[RROWS * 32];     //  4,096 B (per-slot s)
    __shared__ int   jL[RROWS * 32];     //  4,096 B (per-slot j)
    __shared__ float As[RROWS];
    __shared__ unsigned cntL[RROWS];
    __shared__ int   bidx[RROWS];
    __shared__ int   ovf_list[RROWS];
    __shared__ int   ovf_n;
    __shared__ float rv[8];
    __shared__ int   rvi[8];
    __shared__ float wsum[8];

    const int tid = threadIdx.x;         // 0..511
    const int m0  = blockIdx.x * RROWS;
    if (tid == 0) ovf_n = 0;

    // stage z tile, coalesced: 1024 float4, 2 per thread
    #pragma unroll
    for (int i = 0; i < 2; ++i) {
        int li = tid + i * RTHR;         // 0..1023
        int m  = li >> 5, dc = li & 31;
        float4 v = ((const float4*)(z + (size_t)(m0 + m) * DIM))[dc];
        *(float4*)&zs[m * ZS + dc * 4] = v;
    }
    if (tid < RROWS) cntL[tid] = cand_cnt[m0 + tid];
    __syncthreads();
    if (tid < RROWS) As[tid] = np_pairwise_sumsq_128(&zs[tid * ZS]);
    __syncthreads();

    // candidate phase: slot = (row<<5)|ci, one slot per thread x 2
    #pragma unroll
    for (int it = 0; it < 2; ++it) {
        int slot = tid + it * RTHR;      // 0..1023
        int r  = slot >> 5;
        int ci = slot & 31;
        float s = 3.0e38f;
        int   j = 0x7fffffff;
        unsigned cnt = cntL[r];
        if (cnt <= CAP && ci < (int)cnt) {
            j = (int)cand[(size_t)(m0 + r) * CAP + ci];
            const float4* ep = (const float4*)(emb + (size_t)j * DIM);
            const float4* zp = (const float4*)&zs[r * ZS];
            float dot = 0.0f;
            #pragma unroll
            for (int seg = 0; seg < 4; ++seg) dot = dot_seg(zp, ep, seg, dot);
            float t1 = fmaf(-2.0f, dot, As[r]);
            s = __fadd_rn(t1, enorm[j]);
        }
        sL[slot] = s;
        jL[slot] = j;
    }
    __syncthreads();

    // per-row lex-min reduce: 16 lanes/row (in-wave), 2 slots/lane
    {
        int r = tid >> 4, k = tid & 15;
        float bv = sL[r * 32 + k];       int bi = jL[r * 32 + k];
        float v2 = sL[r * 32 + 16 + k];  int i2 = jL[r * 32 + 16 + k];
        if (v2 < bv || (v2 == bv && i2 < bi)) { bv = v2; bi = i2; }
        #pragma unroll
        for (int off = 1; off <= 8; off <<= 1) {
            float v  = __shfl_xor(bv, off, 64);
            int   ix = __shfl_xor(bi, off, 64);
            if (v < bv || (v == bv && ix < bi)) { bv = v; bi = ix; }
        }
        if (k == 0) {
            if (cntL[r] <= CAP) bidx[r] = bi;
            else { int p = atomicAdd(&ovf_n, 1); ovf_list[p] = r; }
        }
    }
    __syncthreads();

    // cooperative exact scan of overflow rows: 512 thr x 4 ascending codes
    const int n_ovf = ovf_n;
    for (int o = 0; o < n_ovf; ++o) {
        const int rl = ovf_list[o];
        const float Ar = As[rl];
        const float4* zp2 = (const float4*)&zs[rl * ZS];
        float bv2 = 3.0e38f;
        int   bi2 = 0x7fffffff;
        for (int jj = 0; jj < 4; ++jj) {
            int j = tid * 4 + jj;        // ascending within thread -> strict <
            const float4* ep = (const float4*)(emb + (size_t)j * DIM);
            float dot = 0.0f;
            #pragma unroll
            for (int seg = 0; seg < 4; ++seg) dot = dot_seg(zp2, ep, seg, dot);
            float t1 = fmaf(-2.0f, dot, Ar);
            float s  = __fadd_rn(t1, enorm[j]);
            if (s < bv2) { bv2 = s; bi2 = j; }
        }
        #pragma unroll
        for (int off = 1; off < 64; off <<= 1) {
            float v  = __shfl_xor(bv2, off, 64);
            int   ix = __shfl_xor(bi2, off, 64);
            if (v < bv2 || (v == bv2 && ix < bi2)) { bv2 = v; bi2 = ix; }
        }
        if ((tid & 63) == 0) { rv[tid >> 6] = bv2; rvi[tid >> 6] = bi2; }
        __syncthreads();
        if (tid == 0) {
            float fv = rv[0]; int fi = rvi[0];
            #pragma unroll
            for (int ww = 1; ww < 8; ++ww) {
                if (rv[ww] < fv || (rv[ww] == fv && rvi[ww] < fi)) { fv = rv[ww]; fi = rvi[ww]; }
            }
            bidx[rl] = fi;
        }
        __syncthreads();
    }

    if (tid < RROWS) out_idx_f[m0 + tid] = (float)bidx[tid];

    // fused gather + straight-through + loss partial (zs still intact)
    float part = 0.0f;
    #pragma unroll
    for (int i = 0; i < 2; ++i) {
        int li = tid + i * RTHR;
        int m  = li >> 5, dc = li & 31;
        int j  = bidx[m];
        float4 q  = ((const float4*)(emb + (size_t)j * DIM))[dc];
        float4 zv = *(const float4*)&zs[m * ZS + dc * 4];
        float4 o;
        o.x = __fadd_rn(zv.x, __fsub_rn(q.x, zv.x));
        o.y = __fadd_rn(zv.y, __fsub_rn(q.y, zv.y));
        o.z = __fadd_rn(zv.z, __fsub_rn(q.z, zv.z));
        o.w = __fadd_rn(zv.w, __fsub_rn(q.w, zv.w));
        ((float4*)out_q)[(size_t)(m0 + m) * 32 + dc] = o;
        float dx = q.x - zv.x, dy = q.y - zv.y, dz = q.z - zv.z, dw = q.w - zv.w;
        part += dx * dx + dy * dy + dz * dz + dw * dw;
    }
    #pragma unroll
    for (int off = 32; off > 0; off >>= 1)
        part += __shfl_down(part, off, 64);
    if ((tid & 63) == 0) wsum[tid >> 6] = part;
    __syncthreads();
    if (tid == 0) {
        float t = 0.0f;
        #pragma unroll
        for (int ww = 0; ww < 8; ++ww) t += wsum[ww];
        atomicAdd(accum, t);
    }
}

// ---------------------------------------------------------------------------
// Kernel 4: loss = (1 + beta) * sum / (N*D), beta = 0.25
// ---------------------------------------------------------------------------
__global__ void finalize_kernel(const float* __restrict__ accum,
                                float* __restrict__ out_loss)
{
    *out_loss = 1.25f * (*accum) / 8388608.0f;
}

// ---------------------------------------------------------------------------
extern "C" void kernel_launch(void* const* d_in, const int* in_sizes, int n_in,
                              void* d_out, int out_size, void* d_ws, size_t ws_size,
                              hipStream_t stream)
{
    const float* z   = (const float*)d_in[0];   // [65536,128]
    const float* emb = (const float*)d_in[1];   // [2048,128]
    float* out = (float*)d_out;                 // q(8388608) | idx-as-f32(65536) | loss(1)

    char*     ws       = (char*)d_ws;
    float*    enorm    = (float*)ws;                          // 8 KB
    float*    accum    = (float*)(ws + 8192);
    unsigned* cand_cnt = (unsigned*)(ws + 16384);             // 256 KB
    ushort*   cand     = (ushort*)(ws + 16384 + 262144);      // 4 MB
    ushort*   emb_bf   = (ushort*)(ws + 16384 + 262144 + 4194304);  // 512 KB

    prep_kernel   <<<NVEC / 256, 256,  0, stream>>>(emb, enorm, accum, emb_bf);
    approx_kernel <<<NVEC / 256, 1024, 0, stream>>>(z, emb_bf, enorm, cand_cnt, cand);
    rerank_kernel <<<NVEC / RROWS, RTHR, 0, stream>>>(z, emb, enorm, cand_cnt, cand,
                                                      out, out + 8388608, accum);
    finalize_kernel<<<1, 1, 0, stream>>>(accum, out + 8388608 + 65536);
}

// Round 8
// 285.903 us; speedup vs baseline: 1.0708x; 1.0708x over previous
//
#include <hip/hip_runtime.h>

#define NUM_EMB 2048
#define DIM     128
#define NVEC    65536            // 64*32*32
// MARGIN: needs >= 2*approx_err + fp32-bucket slop (~2.6e-4). 1e-3 = 4x
// headroom. Proven R7/R8: absmax 0.0. DO NOT ENLARGE (R6's 4e-3 -> 1.9 ms rerank).
// Capture in v-space (v = dot - enorm/2); threshold uses MARGIN/2 in v-units
// == MARGIN in distance units. Superset-capture argument: thr = vmax_sofar -
// MARGIN/2 <= vmax_final - MARGIN/2 at every test => every code within MARGIN
// of the final best is captured. Rerank is exact => absmax 0.
#define MARGIN  1.0e-3f
#define CAP     32               // candidates/row; overflow -> cooperative block scan
#define CHUNK   512              // codes per LDS chunk (R15: visits 9->4)
#define NCHUNK  (NUM_EMB / CHUNK)
#define ES      136              // ushort stride/code in LDS: 272 B -> b128 reads spread banks
#define ZS      132              // float stride/z-row in LDS
#define RROWS   32               // rerank rows/block
#define RTHR    512              // rerank threads/block

typedef float  f32x4 __attribute__((ext_vector_type(4)));
typedef short  s16x8 __attribute__((ext_vector_type(8)));

// RNE float -> bf16 (finite inputs)
__device__ __forceinline__ ushort f2bf(float f) {
    unsigned u = __float_as_uint(f);
    u = (u + 0x7fffu + ((u >> 16) & 1u)) >> 16;
    return (ushort)u;
}

// ---------------------------------------------------------------------------
// numpy pairwise_sum replica for n=128 fp32 applied to v*v (bit-exact vs np —
// verified R2-R8 absmax 0.0).  DO NOT REASSOCIATE.
// ---------------------------------------------------------------------------
__device__ __forceinline__ float np_pairwise_sumsq_128(const float* __restrict__ p)
{
    float r[8];
    #pragma unroll
    for (int j = 0; j < 8; ++j) { float v = p[j]; r[j] = __fmul_rn(v, v); }
    #pragma unroll
    for (int i = 8; i < 128; i += 8)
        #pragma unroll
        for (int j = 0; j < 8; ++j) { float v = p[i + j]; r[j] = __fadd_rn(r[j], __fmul_rn(v, v)); }
    float s01 = __fadd_rn(r[0], r[1]);
    float s23 = __fadd_rn(r[2], r[3]);
    float s45 = __fadd_rn(r[4], r[5]);
    float s67 = __fadd_rn(r[6], r[7]);
    return __fadd_rn(__fadd_rn(s01, s23), __fadd_rn(s45, s67));
}

// exact fp32-replica dot over one 32-k slab (ascending k, single accumulator)
__device__ __forceinline__ float dot_seg(const float4* __restrict__ zp,
                                         const float4* __restrict__ ep,
                                         int seg, float dot)
{
    float4 e[8], zz[8];
    #pragma unroll
    for (int i = 0; i < 8; ++i) { e[i] = ep[seg * 8 + i]; zz[i] = zp[seg * 8 + i]; }
    #pragma unroll
    for (int i = 0; i < 8; ++i) {
        dot = fmaf(zz[i].x, e[i].x, dot);
        dot = fmaf(zz[i].y, e[i].y, dot);
        dot = fmaf(zz[i].z, e[i].z, dot);
        dot = fmaf(zz[i].w, e[i].w, dot);
    }
    return dot;
}

// ---------------------------------------------------------------------------
// Kernel 1: enorm (np-exact) + emb->bf16 + zero accum  (FROZEN, R15)
// ---------------------------------------------------------------------------
__global__ __launch_bounds__(256)
void prep_kernel(const float* __restrict__ emb,
                 float* __restrict__ enorm,
                 float* __restrict__ accum,
                 ushort* __restrict__ emb_bf)
{
    int g = blockIdx.x * 256 + threadIdx.x;
    if (g == 0) *accum = 0.0f;

    float4 v = ((const float4*)emb)[g];          // 65536 float4 == full emb
    ushort4 b;
    b.x = f2bf(v.x); b.y = f2bf(v.y); b.z = f2bf(v.z); b.w = f2bf(v.w);
    ((ushort4*)emb_bf)[g] = b;

    if (g < NUM_EMB)
        enorm[g] = np_pairwise_sumsq_128(emb + (size_t)g * DIM);
}

// ---------------------------------------------------------------------------
// Kernel 2: bf16-MFMA approx filter.  (FROZEN — R16 verified: B-fragment
// reuse, 2 M-tiles/wave x half-codes; left top-5 => < 110us.)
// ---------------------------------------------------------------------------
__global__ __launch_bounds__(1024, 4)
void approx_kernel(const float* __restrict__ z,
                   const ushort* __restrict__ emb_bf,
                   const float* __restrict__ enorm,
                   unsigned* __restrict__ cand_cnt,
                   ushort* __restrict__ cand)
{
    __shared__ __align__(16) ushort eS[CHUNK * ES];   // 139,264 B
    __shared__ float cS[CHUNK];                       //   2,048 B (-0.5*enorm)
    __shared__ float vS[16][32];                      //   2,048 B (pair max exchange)
    __shared__ unsigned cntS[256];                    //   1,024 B

    const int tid  = threadIdx.x;         // 0..1023
    const int w    = tid >> 6;            // wave 0..15
    const int lane = tid & 63;
    const int col  = lane & 15;           // m (A frag) / n (B frag) / D col
    const int quad = lane >> 4;           // k-group / D row-group
    const int rg   = w >> 1;              // row-group 0..7 (32 rows each)
    const int ch   = w & 1;               // code-half 0..1 (256 codes each)
    const int rowbase = blockIdx.x * 256 + rg * 32;

    if (tid < 256) cntS[tid] = 0u;

    // A-fragments: 2 M-tiles x 4 k-tiles, loaded once, fp32->bf16
    s16x8 afrag[2][4];
    #pragma unroll
    for (int mt = 0; mt < 2; ++mt) {
        const float* zr = z + (size_t)(rowbase + mt * 16 + col) * DIM;
        #pragma unroll
        for (int kt = 0; kt < 4; ++kt) {
            const float4* p = (const float4*)(zr + kt * 32 + quad * 8);
            float4 f0 = p[0], f1 = p[1];
            s16x8 a;
            a[0] = (short)f2bf(f0.x); a[1] = (short)f2bf(f0.y);
            a[2] = (short)f2bf(f0.z); a[3] = (short)f2bf(f0.w);
            a[4] = (short)f2bf(f1.x); a[5] = (short)f2bf(f1.y);
            a[6] = (short)f2bf(f1.z); a[7] = (short)f2bf(f1.w);
            afrag[mt][kt] = a;
        }
    }

    const ushort* eH = eS + ch * 256 * ES;   // this wave's code-half in LDS
    const float*  cH = cS + ch * 256;

    // vmax[i], i = mt*4 + r -> local row = mt*16 + quad*4 + r
    float vmax[8], thr[8];
    #pragma unroll
    for (int i = 0; i < 8; ++i) { vmax[i] = -3.0e38f; thr[i] = 3.0e38f; }

    // 4 visits over 4 chunks of 512 codes; capture active from the start.
    for (int vis = 0; vis < NCHUNK; ++vis) {
        if (vis > 0) __syncthreads();        // prev readers done; partner vS visible

        // stage chunk vis: 128 KB, 8 x uint4 per thread, coalesced
        const uint4* src = (const uint4*)(emb_bf + (size_t)vis * CHUNK * DIM);
        #pragma unroll
        for (int i = 0; i < 8; ++i) {
            int li = i * 1024 + tid;         // 0..8191
            int code = li >> 4, fc = li & 15;
            *(uint4*)&eS[code * ES + fc * 8] = src[li];
        }
        if (tid < CHUNK) cS[tid] = -0.5f * enorm[vis * CHUNK + tid];

        // fold partner half's row maxima (through visit vis-1) -> tight thr
        if (vis > 0) {
            #pragma unroll
            for (int i = 0; i < 8; ++i) {
                float v = fmaxf(vmax[i], vS[w ^ 1][(i >> 2) * 16 + quad * 4 + (i & 3)]);
                vmax[i] = v;
                thr[i]  = v - 0.5f * MARGIN;
            }
        }
        __syncthreads();                     // LDS chunk ready

        #pragma unroll 4
        for (int t = 0; t < 16; ++t) {       // 16 x 16 = this wave's 256 codes
            s16x8 bfrag[4];
            #pragma unroll
            for (int kt = 0; kt < 4; ++kt)
                bfrag[kt] = *(const s16x8*)&eH[(t * 16 + col) * ES + kt * 32 + quad * 8];

            float h = cH[t * 16 + col];      // -0.5*enorm of this code
            f32x4 a0 = {h, h, h, h};
            f32x4 a1 = {h, h, h, h};
            #pragma unroll
            for (int kt = 0; kt < 4; ++kt) {
                a0 = __builtin_amdgcn_mfma_f32_16x16x32_bf16(afrag[0][kt], bfrag[kt], a0, 0, 0, 0);
                a1 = __builtin_amdgcn_mfma_f32_16x16x32_bf16(afrag[1][kt], bfrag[kt], a1, 0, 0, 0);
            }

            #pragma unroll
            for (int r = 0; r < 4; ++r) {
                vmax[r]     = fmaxf(vmax[r],     a0[r]);
                vmax[4 + r] = fmaxf(vmax[4 + r], a1[r]);
            }

            // visit 0: threshold still forming -> refresh per-t BEFORE the
            // capture test (superset capture; see MARGIN note).
            if (vis == 0) {
                #pragma unroll
                for (int i = 0; i < 8; ++i) {
                    float v = vmax[i];
                    v = fmaxf(v, __shfl_xor(v, 1, 64));
                    v = fmaxf(v, __shfl_xor(v, 2, 64));
                    v = fmaxf(v, __shfl_xor(v, 4, 64));
                    v = fmaxf(v, __shfl_xor(v, 8, 64));
                    vmax[i] = v;
                    thr[i]  = v - 0.5f * MARGIN;
                }
            }

            const int code_g = vis * CHUNK + ch * 256 + t * 16 + col;
            #pragma unroll
            for (int r = 0; r < 4; ++r) {
                if (a0[r] >= thr[r]) {
                    int row_l = rg * 32 + quad * 4 + r;
                    unsigned pos = atomicAdd(&cntS[row_l], 1u);   // LDS atomic
                    if (pos < CAP)                                 // plain store
                        cand[(size_t)(blockIdx.x * 256 + row_l) * CAP + pos] = (ushort)code_g;
                }
                if (a1[r] >= thr[4 + r]) {
                    int row_l = rg * 32 + 16 + quad * 4 + r;
                    unsigned pos = atomicAdd(&cntS[row_l], 1u);
                    if (pos < CAP)
                        cand[(size_t)(blockIdx.x * 256 + row_l) * CAP + pos] = (ushort)code_g;
                }
            }
        }

        // end-of-visit refresh (vis0 already row-wide from per-t refresh)
        if (vis > 0) {
            #pragma unroll
            for (int i = 0; i < 8; ++i) {
                float v = vmax[i];
                v = fmaxf(v, __shfl_xor(v, 1, 64));
                v = fmaxf(v, __shfl_xor(v, 2, 64));
                v = fmaxf(v, __shfl_xor(v, 4, 64));
                v = fmaxf(v, __shfl_xor(v, 8, 64));
                vmax[i] = v;
                thr[i]  = v - 0.5f * MARGIN;
            }
        }
        // publish this wave's 32-row maxima for the partner wave
        if (col == 0) {
            #pragma unroll
            for (int i = 0; i < 8; ++i)
                vS[w][(i >> 2) * 16 + quad * 4 + (i & 3)] = vmax[i];
        }
    }

    // flush counts (coalesced); payloads already in global
    __syncthreads();
    if (tid < 256) cand_cnt[blockIdx.x * 256 + tid] = cntS[tid];
}

// ---------------------------------------------------------------------------
// Kernel 3: exact fp32-replica re-rank (R17 structure, R18 spill fix).
//
// R17 post-mortem: __launch_bounds__(512,4) min-waves hint -> VGPR capped at
// 64, but dot_seg's e[8]+zz[8] staging = 64 VGPRs live -> SCRATCH SPILL in
// the hot loop (WRITE_SIZE 33->116MB = +83MB spill writes, FETCH 24->52MB,
// VALUBusy flat 7%). Same failure mode as R14. The parallel-slot structure
// itself never got tested.
// R18: __launch_bounds__(RTHR) with NO min-waves (R16 precedent: identical
// dot_seg compiled spill-free at VGPR=112). Expect ~112 VGPR -> 4 waves/SIMD
// -> 2 co-resident 8-wave blocks/CU (~50% occupancy), LDS 26KB non-binding.
// VALIDITY CHECK: VGPR must be >64 and WRITE_SIZE ~33MB; else void.
// Structure (R17, unchanged): 512 thr x 32 rows, one (row,ci) candidate dot
// per thread (slots 0..1023, lanes 0-31 of each wave-half share a row ->
// z broadcast + coalesced cand reads), per-row lex-min (s asc, j asc) over
// LDS slots — order-independent, bit-identical selection. dot_seg order
// UNCHANGED. Overflow: block-cooperative scan, 512 thr x 4 ascending codes.
// ---------------------------------------------------------------------------
__global__ __launch_bounds__(RTHR)
void rerank_kernel(const float* __restrict__ z,
                   const float* __restrict__ emb,
                   const float* __restrict__ enorm,
                   const unsigned* __restrict__ cand_cnt,
                   const ushort* __restrict__ cand,
                   float* __restrict__ out_q,
                   float* __restrict__ out_idx_f,
                   float* __restrict__ accum)
{
    __shared__ float zs[RROWS * ZS];     // 16,896 B
    __shared__ float sL[RROWS * 32];     //  4,096 B (per-slot s)
    __shared__ int   jL[RROWS * 32];     //  4,096 B (per-slot j)
    __shared__ float As[RROWS];
    __shared__ unsigned cntL[RROWS];
    __shared__ int   bidx[RROWS];
    __shared__ int   ovf_list[RROWS];
    __shared__ int   ovf_n;
    __shared__ float rv[8];
    __shared__ int   rvi[8];
    __shared__ float wsum[8];

    const int tid = threadIdx.x;         // 0..511
    const int m0  = blockIdx.x * RROWS;
    if (tid == 0) ovf_n = 0;

    // stage z tile, coalesced: 1024 float4, 2 per thread
    #pragma unroll
    for (int i = 0; i < 2; ++i) {
        int li = tid + i * RTHR;         // 0..1023
        int m  = li >> 5, dc = li & 31;
        float4 v = ((const float4*)(z + (size_t)(m0 + m) * DIM))[dc];
        *(float4*)&zs[m * ZS + dc * 4] = v;
    }
    if (tid < RROWS) cntL[tid] = cand_cnt[m0 + tid];
    __syncthreads();
    if (tid < RROWS) As[tid] = np_pairwise_sumsq_128(&zs[tid * ZS]);
    __syncthreads();

    // candidate phase: slot = (row<<5)|ci, one slot per thread x 2
    #pragma unroll
    for (int it = 0; it < 2; ++it) {
        int slot = tid + it * RTHR;      // 0..1023
        int r  = slot >> 5;
        int ci = slot & 31;
        float s = 3.0e38f;
        int   j = 0x7fffffff;
        unsigned cnt = cntL[r];
        if (cnt <= CAP && ci < (int)cnt) {
            j = (int)cand[(size_t)(m0 + r) * CAP + ci];
            const float4* ep = (const float4*)(emb + (size_t)j * DIM);
            const float4* zp = (const float4*)&zs[r * ZS];
            float dot = 0.0f;
            #pragma unroll
            for (int seg = 0; seg < 4; ++seg) dot = dot_seg(zp, ep, seg, dot);
            float t1 = fmaf(-2.0f, dot, As[r]);
            s = __fadd_rn(t1, enorm[j]);
        }
        sL[slot] = s;
        jL[slot] = j;
    }
    __syncthreads();

    // per-row lex-min reduce: 16 lanes/row (in-wave), 2 slots/lane
    {
        int r = tid >> 4, k = tid & 15;
        float bv = sL[r * 32 + k];       int bi = jL[r * 32 + k];
        float v2 = sL[r * 32 + 16 + k];  int i2 = jL[r * 32 + 16 + k];
        if (v2 < bv || (v2 == bv && i2 < bi)) { bv = v2; bi = i2; }
        #pragma unroll
        for (int off = 1; off <= 8; off <<= 1) {
            float v  = __shfl_xor(bv, off, 64);
            int   ix = __shfl_xor(bi, off, 64);
            if (v < bv || (v == bv && ix < bi)) { bv = v; bi = ix; }
        }
        if (k == 0) {
            if (cntL[r] <= CAP) bidx[r] = bi;
            else { int p = atomicAdd(&ovf_n, 1); ovf_list[p] = r; }
        }
    }
    __syncthreads();

    // cooperative exact scan of overflow rows: 512 thr x 4 ascending codes
    const int n_ovf = ovf_n;
    for (int o = 0; o < n_ovf; ++o) {
        const int rl = ovf_list[o];
        const float Ar = As[rl];
        const float4* zp2 = (const float4*)&zs[rl * ZS];
        float bv2 = 3.0e38f;
        int   bi2 = 0x7fffffff;
        for (int jj = 0; jj < 4; ++jj) {
            int j = tid * 4 + jj;        // ascending within thread -> strict <
            const float4* ep = (const float4*)(emb + (size_t)j * DIM);
            float dot = 0.0f;
            #pragma unroll
            for (int seg = 0; seg < 4; ++seg) dot = dot_seg(zp2, ep, seg, dot);
            float t1 = fmaf(-2.0f, dot, Ar);
            float s  = __fadd_rn(t1, enorm[j]);
            if (s < bv2) { bv2 = s; bi2 = j; }
        }
        #pragma unroll
        for (int off = 1; off < 64; off <<= 1) {
            float v  = __shfl_xor(bv2, off, 64);
            int   ix = __shfl_xor(bi2, off, 64);
            if (v < bv2 || (v == bv2 && ix < bi2)) { bv2 = v; bi2 = ix; }
        }
        if ((tid & 63) == 0) { rv[tid >> 6] = bv2; rvi[tid >> 6] = bi2; }
        __syncthreads();
        if (tid == 0) {
            float fv = rv[0]; int fi = rvi[0];
            #pragma unroll
            for (int ww = 1; ww < 8; ++ww) {
                if (rv[ww] < fv || (rv[ww] == fv && rvi[ww] < fi)) { fv = rv[ww]; fi = rvi[ww]; }
            }
            bidx[rl] = fi;
        }
        __syncthreads();
    }

    if (tid < RROWS) out_idx_f[m0 + tid] = (float)bidx[tid];

    // fused gather + straight-through + loss partial (zs still intact)
    float part = 0.0f;
    #pragma unroll
    for (int i = 0; i < 2; ++i) {
        int li = tid + i * RTHR;
        int m  = li >> 5, dc = li & 31;
        int j  = bidx[m];
        float4 q  = ((const float4*)(emb + (size_t)j * DIM))[dc];
        float4 zv = *(const float4*)&zs[m * ZS + dc * 4];
        float4 o;
        o.x = __fadd_rn(zv.x, __fsub_rn(q.x, zv.x));
        o.y = __fadd_rn(zv.y, __fsub_rn(q.y, zv.y));
        o.z = __fadd_rn(zv.z, __fsub_rn(q.z, zv.z));
        o.w = __fadd_rn(zv.w, __fsub_rn(q.w, zv.w));
        ((float4*)out_q)[(size_t)(m0 + m) * 32 + dc] = o;
        float dx = q.x - zv.x, dy = q.y - zv.y, dz = q.z - zv.z, dw = q.w - zv.w;
        part += dx * dx + dy * dy + dz * dz + dw * dw;
    }
    #pragma unroll
    for (int off = 32; off > 0; off >>= 1)
        part += __shfl_down(part, off, 64);
    if ((tid & 63) == 0) wsum[tid >> 6] = part;
    __syncthreads();
    if (tid == 0) {
        float t = 0.0f;
        #pragma unroll
        for (int ww = 0; ww < 8; ++ww) t += wsum[ww];
        atomicAdd(accum, t);
    }
}

// ---------------------------------------------------------------------------
// Kernel 4: loss = (1 + beta) * sum / (N*D), beta = 0.25
// ---------------------------------------------------------------------------
__global__ void finalize_kernel(const float* __restrict__ accum,
                                float* __restrict__ out_loss)
{
    *out_loss = 1.25f * (*accum) / 8388608.0f;
}

// ---------------------------------------------------------------------------
extern "C" void kernel_launch(void* const* d_in, const int* in_sizes, int n_in,
                              void* d_out, int out_size, void* d_ws, size_t ws_size,
                              hipStream_t stream)
{
    const float* z   = (const float*)d_in[0];   // [65536,128]
    const float* emb = (const float*)d_in[1];   // [2048,128]
    float* out = (float*)d_out;                 // q(8388608) | idx-as-f32(65536) | loss(1)

    char*     ws       = (char*)d_ws;
    float*    enorm    = (float*)ws;                          // 8 KB
    float*    accum    = (float*)(ws + 8192);
    unsigned* cand_cnt = (unsigned*)(ws + 16384);             // 256 KB
    ushort*   cand     = (ushort*)(ws + 16384 + 262144);      // 4 MB
    ushort*   emb_bf   = (ushort*)(ws + 16384 + 262144 + 4194304);  // 512 KB

    prep_kernel   <<<NVEC / 256, 256,  0, stream>>>(emb, enorm, accum, emb_bf);
    approx_kernel <<<NVEC / 256, 1024, 0, stream>>>(z, emb_bf, enorm, cand_cnt, cand);
    rerank_kernel <<<NVEC / RROWS, RTHR, 0, stream>>>(z, emb, enorm, cand_cnt, cand,
                                                      out, out + 8388608, accum);
    finalize_kernel<<<1, 1, 0, stream>>>(accum, out + 8388608 + 65536);
}

// Round 9
// 229.969 us; speedup vs baseline: 1.3312x; 1.2432x over previous
//
#include <hip/hip_runtime.h>

#define NUM_EMB 2048
#define DIM     128
#define NVEC    65536            // 64*32*32
// MARGIN: needs >= 2*approx_err + fp32-bucket slop (~2.6e-4). 1e-3 = 4x
// headroom. Proven R7/R8: absmax 0.0. DO NOT ENLARGE (R6's 4e-3 -> 1.9 ms rerank).
// Capture in v-space (v = dot - enorm/2); threshold uses MARGIN/2 in v-units
// == MARGIN in distance units. Superset argument: at every test, thr =
// (running max over some prefix) - MARGIN/2 <= vmax_final - MARGIN/2, so any
// code within MARGIN of the final best passes. TIGHTER prefixes only reduce
// false captures. Rerank is exact => absmax 0.
#define MARGIN  1.0e-3f
#define CAP     32               // candidates/row; overflow -> cooperative block scan
#define CHUNK   512              // codes per LDS chunk
#define NCHUNK  (NUM_EMB / CHUNK)
#define ES      136              // ushort stride/code in LDS: 272 B -> b128 reads spread banks
#define ZS      132              // float stride/z-row in LDS
#define RROWS   32               // rerank rows/block
#define RTHR    512              // rerank threads/block

typedef float  f32x4 __attribute__((ext_vector_type(4)));
typedef short  s16x8 __attribute__((ext_vector_type(8)));

// RNE float -> bf16 (finite inputs)
__device__ __forceinline__ ushort f2bf(float f) {
    unsigned u = __float_as_uint(f);
    u = (u + 0x7fffu + ((u >> 16) & 1u)) >> 16;
    return (ushort)u;
}

// ---------------------------------------------------------------------------
// numpy pairwise_sum replica for n=128 fp32 applied to v*v (bit-exact vs np —
// verified R2-R8 absmax 0.0).  DO NOT REASSOCIATE.
// ---------------------------------------------------------------------------
__device__ __forceinline__ float np_pairwise_sumsq_128(const float* __restrict__ p)
{
    float r[8];
    #pragma unroll
    for (int j = 0; j < 8; ++j) { float v = p[j]; r[j] = __fmul_rn(v, v); }
    #pragma unroll
    for (int i = 8; i < 128; i += 8)
        #pragma unroll
        for (int j = 0; j < 8; ++j) { float v = p[i + j]; r[j] = __fadd_rn(r[j], __fmul_rn(v, v)); }
    float s01 = __fadd_rn(r[0], r[1]);
    float s23 = __fadd_rn(r[2], r[3]);
    float s45 = __fadd_rn(r[4], r[5]);
    float s67 = __fadd_rn(r[6], r[7]);
    return __fadd_rn(__fadd_rn(s01, s23), __fadd_rn(s45, s67));
}

// exact fp32-replica dot over one 32-k slab (ascending k, single accumulator)
__device__ __forceinline__ float dot_seg(const float4* __restrict__ zp,
                                         const float4* __restrict__ ep,
                                         int seg, float dot)
{
    float4 e[8], zz[8];
    #pragma unroll
    for (int i = 0; i < 8; ++i) { e[i] = ep[seg * 8 + i]; zz[i] = zp[seg * 8 + i]; }
    #pragma unroll
    for (int i = 0; i < 8; ++i) {
        dot = fmaf(zz[i].x, e[i].x, dot);
        dot = fmaf(zz[i].y, e[i].y, dot);
        dot = fmaf(zz[i].z, e[i].z, dot);
        dot = fmaf(zz[i].w, e[i].w, dot);
    }
    return dot;
}

// ---------------------------------------------------------------------------
// Kernel 1: enorm (np-exact) + emb->bf16 + zero accum  (FROZEN, R15)
// ---------------------------------------------------------------------------
__global__ __launch_bounds__(256)
void prep_kernel(const float* __restrict__ emb,
                 float* __restrict__ enorm,
                 float* __restrict__ accum,
                 ushort* __restrict__ emb_bf)
{
    int g = blockIdx.x * 256 + threadIdx.x;
    if (g == 0) *accum = 0.0f;

    float4 v = ((const float4*)emb)[g];          // 65536 float4 == full emb
    ushort4 b;
    b.x = f2bf(v.x); b.y = f2bf(v.y); b.z = f2bf(v.z); b.w = f2bf(v.w);
    ((ushort4*)emb_bf)[g] = b;

    if (g < NUM_EMB)
        enorm[g] = np_pairwise_sumsq_128(emb + (size_t)g * DIM);
}

// ---------------------------------------------------------------------------
// Kernel 2: bf16-MFMA approx filter.
//
// R19 (tight capture — attack candidate COUNT, not gather mechanics):
//   R16/R18 post-mortems: two different rerank structures (serial-lane,
//   parallel-slot) both land 110-129us with all pipes <10% => the wall
//   scales with capture volume: ~13 cand/row from R15's progressive vis-0
//   threshold (running-max record cohort), each costing a 64-distinct-line
//   scatter gather in rerank; plus rare cnt>CAP rows triggering 1MB
//   block-serial overflow scans.
//   Fix: vis-0 pre-pass over the wave's own chunk-0 half, MAX-ONLY (data is
//   LDS-resident; +128 MFMA/wave, MfmaUtil only 12% -> cheap), one shuffle
//   refresh -> TIGHT thr; then capture passes test against it. Removes the
//   per-t shuffle refresh (512 shuffle-ops/wave). Expected cnt 13 -> ~1-3,
//   overflow ~extinct. Margin guarantee per MARGIN note (prefix-max form).
// MFMA 16x16x32 bf16 layouts HW-verified (m89/m91).
// ---------------------------------------------------------------------------
__global__ __launch_bounds__(1024, 4)
void approx_kernel(const float* __restrict__ z,
                   const ushort* __restrict__ emb_bf,
                   const float* __restrict__ enorm,
                   unsigned* __restrict__ cand_cnt,
                   ushort* __restrict__ cand)
{
    __shared__ __align__(16) ushort eS[CHUNK * ES];   // 139,264 B
    __shared__ float cS[CHUNK];                       //   2,048 B (-0.5*enorm)
    __shared__ float vS[16][32];                      //   2,048 B (pair max exchange)
    __shared__ unsigned cntS[256];                    //   1,024 B

    const int tid  = threadIdx.x;         // 0..1023
    const int w    = tid >> 6;            // wave 0..15
    const int lane = tid & 63;
    const int col  = lane & 15;           // m (A frag) / n (B frag) / D col
    const int quad = lane >> 4;           // k-group / D row-group
    const int rg   = w >> 1;              // row-group 0..7 (32 rows each)
    const int ch   = w & 1;               // code-half 0..1 (256 codes each)
    const int rowbase = blockIdx.x * 256 + rg * 32;

    if (tid < 256) cntS[tid] = 0u;

    // A-fragments: 2 M-tiles x 4 k-tiles, loaded once, fp32->bf16
    s16x8 afrag[2][4];
    #pragma unroll
    for (int mt = 0; mt < 2; ++mt) {
        const float* zr = z + (size_t)(rowbase + mt * 16 + col) * DIM;
        #pragma unroll
        for (int kt = 0; kt < 4; ++kt) {
            const float4* p = (const float4*)(zr + kt * 32 + quad * 8);
            float4 f0 = p[0], f1 = p[1];
            s16x8 a;
            a[0] = (short)f2bf(f0.x); a[1] = (short)f2bf(f0.y);
            a[2] = (short)f2bf(f0.z); a[3] = (short)f2bf(f0.w);
            a[4] = (short)f2bf(f1.x); a[5] = (short)f2bf(f1.y);
            a[6] = (short)f2bf(f1.z); a[7] = (short)f2bf(f1.w);
            afrag[mt][kt] = a;
        }
    }

    const ushort* eH = eS + ch * 256 * ES;   // this wave's code-half in LDS
    const float*  cH = cS + ch * 256;

    // vmax[i], i = mt*4 + r -> local row = mt*16 + quad*4 + r
    float vmax[8], thr[8];
    #pragma unroll
    for (int i = 0; i < 8; ++i) { vmax[i] = -3.0e38f; thr[i] = 3.0e38f; }

    // 4 visits over 4 chunks of 512 codes.
    for (int vis = 0; vis < NCHUNK; ++vis) {
        if (vis > 0) __syncthreads();        // prev readers done; partner vS visible

        // stage chunk vis: 128 KB, 8 x uint4 per thread, coalesced
        const uint4* src = (const uint4*)(emb_bf + (size_t)vis * CHUNK * DIM);
        #pragma unroll
        for (int i = 0; i < 8; ++i) {
            int li = i * 1024 + tid;         // 0..8191
            int code = li >> 4, fc = li & 15;
            *(uint4*)&eS[code * ES + fc * 8] = src[li];
        }
        if (tid < CHUNK) cS[tid] = -0.5f * enorm[vis * CHUNK + tid];

        // fold partner half's row maxima (through visit vis-1) -> tight thr
        if (vis > 0) {
            #pragma unroll
            for (int i = 0; i < 8; ++i) {
                float v = fmaxf(vmax[i], vS[w ^ 1][(i >> 2) * 16 + quad * 4 + (i & 3)]);
                vmax[i] = v;
                thr[i]  = v - 0.5f * MARGIN;
            }
        }
        __syncthreads();                     // LDS chunk ready

        // vis 0: MAX-ONLY pre-pass over own half (LDS-resident; no capture),
        // then one shuffle refresh -> tight thr for the capture pass below.
        if (vis == 0) {
            #pragma unroll 4
            for (int t = 0; t < 16; ++t) {
                s16x8 bfrag[4];
                #pragma unroll
                for (int kt = 0; kt < 4; ++kt)
                    bfrag[kt] = *(const s16x8*)&eH[(t * 16 + col) * ES + kt * 32 + quad * 8];
                float h = cH[t * 16 + col];
                f32x4 a0 = {h, h, h, h};
                f32x4 a1 = {h, h, h, h};
                #pragma unroll
                for (int kt = 0; kt < 4; ++kt) {
                    a0 = __builtin_amdgcn_mfma_f32_16x16x32_bf16(afrag[0][kt], bfrag[kt], a0, 0, 0, 0);
                    a1 = __builtin_amdgcn_mfma_f32_16x16x32_bf16(afrag[1][kt], bfrag[kt], a1, 0, 0, 0);
                }
                #pragma unroll
                for (int r = 0; r < 4; ++r) {
                    vmax[r]     = fmaxf(vmax[r],     a0[r]);
                    vmax[4 + r] = fmaxf(vmax[4 + r], a1[r]);
                }
            }
            #pragma unroll
            for (int i = 0; i < 8; ++i) {
                float v = vmax[i];
                v = fmaxf(v, __shfl_xor(v, 1, 64));
                v = fmaxf(v, __shfl_xor(v, 2, 64));
                v = fmaxf(v, __shfl_xor(v, 4, 64));
                v = fmaxf(v, __shfl_xor(v, 8, 64));
                vmax[i] = v;
                thr[i]  = v - 0.5f * MARGIN;
            }
        }

        // capture pass (all visits): fixed thr within the pass (prefix-max
        // form => superset capture; vmax still tracked for later visits)
        #pragma unroll 4
        for (int t = 0; t < 16; ++t) {       // 16 x 16 = this wave's 256 codes
            s16x8 bfrag[4];
            #pragma unroll
            for (int kt = 0; kt < 4; ++kt)
                bfrag[kt] = *(const s16x8*)&eH[(t * 16 + col) * ES + kt * 32 + quad * 8];

            float h = cH[t * 16 + col];      // -0.5*enorm of this code
            f32x4 a0 = {h, h, h, h};
            f32x4 a1 = {h, h, h, h};
            #pragma unroll
            for (int kt = 0; kt < 4; ++kt) {
                a0 = __builtin_amdgcn_mfma_f32_16x16x32_bf16(afrag[0][kt], bfrag[kt], a0, 0, 0, 0);
                a1 = __builtin_amdgcn_mfma_f32_16x16x32_bf16(afrag[1][kt], bfrag[kt], a1, 0, 0, 0);
            }

            #pragma unroll
            for (int r = 0; r < 4; ++r) {
                vmax[r]     = fmaxf(vmax[r],     a0[r]);
                vmax[4 + r] = fmaxf(vmax[4 + r], a1[r]);
            }

            const int code_g = vis * CHUNK + ch * 256 + t * 16 + col;
            #pragma unroll
            for (int r = 0; r < 4; ++r) {
                if (a0[r] >= thr[r]) {
                    int row_l = rg * 32 + quad * 4 + r;
                    unsigned pos = atomicAdd(&cntS[row_l], 1u);   // LDS atomic
                    if (pos < CAP)                                 // plain store
                        cand[(size_t)(blockIdx.x * 256 + row_l) * CAP + pos] = (ushort)code_g;
                }
                if (a1[r] >= thr[4 + r]) {
                    int row_l = rg * 32 + 16 + quad * 4 + r;
                    unsigned pos = atomicAdd(&cntS[row_l], 1u);
                    if (pos < CAP)
                        cand[(size_t)(blockIdx.x * 256 + row_l) * CAP + pos] = (ushort)code_g;
                }
            }
        }

        // end-of-visit refresh (vis0's thr already row-wide; vmax unchanged
        // during its capture pass, but refresh is harmless and keeps thr
        // current entering the next visit)
        if (vis > 0) {
            #pragma unroll
            for (int i = 0; i < 8; ++i) {
                float v = vmax[i];
                v = fmaxf(v, __shfl_xor(v, 1, 64));
                v = fmaxf(v, __shfl_xor(v, 2, 64));
                v = fmaxf(v, __shfl_xor(v, 4, 64));
                v = fmaxf(v, __shfl_xor(v, 8, 64));
                vmax[i] = v;
                thr[i]  = v - 0.5f * MARGIN;
            }
        }
        // publish this wave's 32-row maxima for the partner wave
        if (col == 0) {
            #pragma unroll
            for (int i = 0; i < 8; ++i)
                vS[w][(i >> 2) * 16 + quad * 4 + (i & 3)] = vmax[i];
        }
    }

    // flush counts (coalesced); payloads already in global
    __syncthreads();
    if (tid < 256) cand_cnt[blockIdx.x * 256 + tid] = cntS[tid];
}

// ---------------------------------------------------------------------------
// Kernel 3: exact fp32-replica re-rank.
//
// R19: cnt==1 fast path — capture is a superset containing the true argmin;
// a singleton candidate set IS the answer (no tie possible, no dot needed).
// Dots only for cnt in [2,CAP]; overflow scan unchanged (rare with tight
// capture). As computed 8-lanes/row with the BIT-IDENTICAL op DAG (same
// pairwise tree, IEEE add commutativity) — 1500cy -> ~100cy.
// Structure otherwise R18 (parallel slots, spill-free at VGPR=100).
// ---------------------------------------------------------------------------
__global__ __launch_bounds__(RTHR)
void rerank_kernel(const float* __restrict__ z,
                   const float* __restrict__ emb,
                   const float* __restrict__ enorm,
                   const unsigned* __restrict__ cand_cnt,
                   const ushort* __restrict__ cand,
                   float* __restrict__ out_q,
                   float* __restrict__ out_idx_f,
                   float* __restrict__ accum)
{
    __shared__ float zs[RROWS * ZS];     // 16,896 B
    __shared__ float sL[RROWS * 32];     //  4,096 B (per-slot s)
    __shared__ int   jL[RROWS * 32];     //  4,096 B (per-slot j)
    __shared__ float As[RROWS];
    __shared__ unsigned cntL[RROWS];
    __shared__ int   bidx[RROWS];
    __shared__ int   ovf_list[RROWS];
    __shared__ int   ovf_n;
    __shared__ float rv[8];
    __shared__ int   rvi[8];
    __shared__ float wsum[8];

    const int tid = threadIdx.x;         // 0..511
    const int m0  = blockIdx.x * RROWS;
    if (tid == 0) ovf_n = 0;

    // stage z tile, coalesced: 1024 float4, 2 per thread
    #pragma unroll
    for (int i = 0; i < 2; ++i) {
        int li = tid + i * RTHR;         // 0..1023
        int m  = li >> 5, dc = li & 31;
        float4 v = ((const float4*)(z + (size_t)(m0 + m) * DIM))[dc];
        *(float4*)&zs[m * ZS + dc * 4] = v;
    }
    if (tid < RROWS) cntL[tid] = cand_cnt[m0 + tid];
    __syncthreads();

    // As: 8 lanes/row, exact np_pairwise tree (r[j] chains are independent;
    // combine order identical; IEEE add is commutative => bit-exact).
    if (tid < 256) {
        int m = tid >> 3, jj = tid & 7;  // 8 rows/wave, groups never straddle waves
        const float* p = &zs[m * ZS];
        float v0 = p[jj];
        float r = __fmul_rn(v0, v0);
        #pragma unroll
        for (int i = 8; i < 128; i += 8) { float v = p[i + jj]; r = __fadd_rn(r, __fmul_rn(v, v)); }
        float rx = __shfl_xor(r, 1, 64);
        float s2 = __fadd_rn(r, rx);         // lanes {0,2,4,6}: s01,s23,s45,s67
        float s2x = __shfl_xor(s2, 2, 64);
        float s4 = __fadd_rn(s2, s2x);       // lane0: s01+s23, lane4: s45+s67
        float s4x = __shfl_xor(s4, 4, 64);
        float s8 = __fadd_rn(s4, s4x);       // lane0: (s01+s23)+(s45+s67)
        if (jj == 0) As[m] = s8;
    }
    __syncthreads();

    // candidate phase: slot = (row<<5)|ci, one slot per thread x 2.
    // cnt==1 rows skip the dot entirely (answer is the single candidate).
    #pragma unroll
    for (int it = 0; it < 2; ++it) {
        int slot = tid + it * RTHR;      // 0..1023
        int r  = slot >> 5;
        int ci = slot & 31;
        float s = 3.0e38f;
        int   j = 0x7fffffff;
        unsigned cnt = cntL[r];
        if (cnt >= 2u && cnt <= CAP && ci < (int)cnt) {
            j = (int)cand[(size_t)(m0 + r) * CAP + ci];
            const float4* ep = (const float4*)(emb + (size_t)j * DIM);
            const float4* zp = (const float4*)&zs[r * ZS];
            float dot = 0.0f;
            #pragma unroll
            for (int seg = 0; seg < 4; ++seg) dot = dot_seg(zp, ep, seg, dot);
            float t1 = fmaf(-2.0f, dot, As[r]);
            s = __fadd_rn(t1, enorm[j]);
        }
        sL[slot] = s;
        jL[slot] = j;
    }
    __syncthreads();

    // per-row lex-min reduce: 16 lanes/row (in-wave), 2 slots/lane
    {
        int r = tid >> 4, k = tid & 15;
        float bv = sL[r * 32 + k];       int bi = jL[r * 32 + k];
        float v2 = sL[r * 32 + 16 + k];  int i2 = jL[r * 32 + 16 + k];
        if (v2 < bv || (v2 == bv && i2 < bi)) { bv = v2; bi = i2; }
        #pragma unroll
        for (int off = 1; off <= 8; off <<= 1) {
            float v  = __shfl_xor(bv, off, 64);
            int   ix = __shfl_xor(bi, off, 64);
            if (v < bv || (v == bv && ix < bi)) { bv = v; bi = ix; }
        }
        if (k == 0) {
            unsigned cnt = cntL[r];
            if (cnt == 1u)       bidx[r] = (int)cand[(size_t)(m0 + r) * CAP];
            else if (cnt <= CAP) bidx[r] = bi;
            else { int p = atomicAdd(&ovf_n, 1); ovf_list[p] = r; }
        }
    }
    __syncthreads();

    // cooperative exact scan of overflow rows: 512 thr x 4 ascending codes
    const int n_ovf = ovf_n;
    for (int o = 0; o < n_ovf; ++o) {
        const int rl = ovf_list[o];
        const float Ar = As[rl];
        const float4* zp2 = (const float4*)&zs[rl * ZS];
        float bv2 = 3.0e38f;
        int   bi2 = 0x7fffffff;
        for (int jj = 0; jj < 4; ++jj) {
            int j = tid * 4 + jj;        // ascending within thread -> strict <
            const float4* ep = (const float4*)(emb + (size_t)j * DIM);
            float dot = 0.0f;
            #pragma unroll
            for (int seg = 0; seg < 4; ++seg) dot = dot_seg(zp2, ep, seg, dot);
            float t1 = fmaf(-2.0f, dot, Ar);
            float s  = __fadd_rn(t1, enorm[j]);
            if (s < bv2) { bv2 = s; bi2 = j; }
        }
        #pragma unroll
        for (int off = 1; off < 64; off <<= 1) {
            float v  = __shfl_xor(bv2, off, 64);
            int   ix = __shfl_xor(bi2, off, 64);
            if (v < bv2 || (v == bv2 && ix < bi2)) { bv2 = v; bi2 = ix; }
        }
        if ((tid & 63) == 0) { rv[tid >> 6] = bv2; rvi[tid >> 6] = bi2; }
        __syncthreads();
        if (tid == 0) {
            float fv = rv[0]; int fi = rvi[0];
            #pragma unroll
            for (int ww = 1; ww < 8; ++ww) {
                if (rv[ww] < fv || (rv[ww] == fv && rvi[ww] < fi)) { fv = rv[ww]; fi = rvi[ww]; }
            }
            bidx[rl] = fi;
        }
        __syncthreads();
    }

    if (tid < RROWS) out_idx_f[m0 + tid] = (float)bidx[tid];

    // fused gather + straight-through + loss partial (zs still intact)
    float part = 0.0f;
    #pragma unroll
    for (int i = 0; i < 2; ++i) {
        int li = tid + i * RTHR;
        int m  = li >> 5, dc = li & 31;
        int j  = bidx[m];
        float4 q  = ((const float4*)(emb + (size_t)j * DIM))[dc];
        float4 zv = *(const float4*)&zs[m * ZS + dc * 4];
        float4 o;
        o.x = __fadd_rn(zv.x, __fsub_rn(q.x, zv.x));
        o.y = __fadd_rn(zv.y, __fsub_rn(q.y, zv.y));
        o.z = __fadd_rn(zv.z, __fsub_rn(q.z, zv.z));
        o.w = __fadd_rn(zv.w, __fsub_rn(q.w, zv.w));
        ((float4*)out_q)[(size_t)(m0 + m) * 32 + dc] = o;
        float dx = q.x - zv.x, dy = q.y - zv.y, dz = q.z - zv.z, dw = q.w - zv.w;
        part += dx * dx + dy * dy + dz * dz + dw * dw;
    }
    #pragma unroll
    for (int off = 32; off > 0; off >>= 1)
        part += __shfl_down(part, off, 64);
    if ((tid & 63) == 0) wsum[tid >> 6] = part;
    __syncthreads();
    if (tid == 0) {
        float t = 0.0f;
        #pragma unroll
        for (int ww = 0; ww < 8; ++ww) t += wsum[ww];
        atomicAdd(accum, t);
    }
}

// ---------------------------------------------------------------------------
// Kernel 4: loss = (1 + beta) * sum / (N*D), beta = 0.25
// ---------------------------------------------------------------------------
__global__ void finalize_kernel(const float* __restrict__ accum,
                                float* __restrict__ out_loss)
{
    *out_loss = 1.25f * (*accum) / 8388608.0f;
}

// ---------------------------------------------------------------------------
extern "C" void kernel_launch(void* const* d_in, const int* in_sizes, int n_in,
                              void* d_out, int out_size, void* d_ws, size_t ws_size,
                              hipStream_t stream)
{
    const float* z   = (const float*)d_in[0];   // [65536,128]
    const float* emb = (const float*)d_in[1];   // [2048,128]
    float* out = (float*)d_out;                 // q(8388608) | idx-as-f32(65536) | loss(1)

    char*     ws       = (char*)d_ws;
    float*    enorm    = (float*)ws;                          // 8 KB
    float*    accum    = (float*)(ws + 8192);
    unsigned* cand_cnt = (unsigned*)(ws + 16384);             // 256 KB
    ushort*   cand     = (ushort*)(ws + 16384 + 262144);      // 4 MB
    ushort*   emb_bf   = (ushort*)(ws + 16384 + 262144 + 4194304);  // 512 KB

    prep_kernel   <<<NVEC / 256, 256,  0, stream>>>(emb, enorm, accum, emb_bf);
    approx_kernel <<<NVEC / 256, 1024, 0, stream>>>(z, emb_bf, enorm, cand_cnt, cand);
    rerank_kernel <<<NVEC / RROWS, RTHR, 0, stream>>>(z, emb, enorm, cand_cnt, cand,
                                                      out, out + 8388608, accum);
    finalize_kernel<<<1, 1, 0, stream>>>(accum, out + 8388608 + 65536);
}